// Round 1
// baseline (233.973 us; speedup 1.0000x reference)
//
#include <hip/hip_runtime.h>

typedef __attribute__((ext_vector_type(8))) short bf16x8;
typedef __attribute__((ext_vector_type(8))) unsigned short u16x8;
typedef __attribute__((ext_vector_type(4))) float f32x4;

constexpr int BH  = 64;    // B*H
constexpr int SEQ = 4096;  // N
constexpr int DIM = 64;    // D
constexpr int PM  = 256;   // M (proj_len)

__device__ __forceinline__ unsigned short f2bf(float f){
    unsigned int u = __float_as_uint(f);
    return (unsigned short)((u + 0x7fffu + ((u >> 16) & 1u)) >> 16);
}
__device__ __forceinline__ float bf2f(unsigned short h){
    return __uint_as_float(((unsigned int)h) << 16);
}

// ---------------- kernel 1: E [N][M] f32 -> Et_hi/Et_lo [M][N] bf16 (split) ----------------
__global__ __launch_bounds__(256) void prep_e_kernel(const float* __restrict__ E,
                                                     unsigned short* __restrict__ Et_hi,
                                                     unsigned short* __restrict__ Et_lo){
    __shared__ float T[64][65];
    int n0 = (blockIdx.x & 63) * 64;
    int m0 = (blockIdx.x >> 6) * 64;
    int t = threadIdx.x;
    #pragma unroll
    for (int i = 0; i < 16; ++i){
        int idx = t + i * 256;
        int nl = idx >> 6, ml = idx & 63;
        T[nl][ml] = E[(size_t)(n0 + nl) * PM + (m0 + ml)];
    }
    __syncthreads();
    #pragma unroll
    for (int i = 0; i < 16; ++i){
        int idx = t + i * 256;
        int ml = idx >> 6, nl = idx & 63;
        float v = T[nl][ml];
        unsigned short h = f2bf(v);
        unsigned short lo = f2bf(v - bf2f(h));
        size_t o = (size_t)(m0 + ml) * SEQ + (n0 + nl);
        Et_hi[o] = h;
        Et_lo[o] = lo;
    }
}

// ---------------- kernel 2: projections ----------------
// K_proj[bh][m][d] = sum_n E[n][m]*K[bh][n][d]  (split hi/lo bf16 out)
// VptT [bh][d][m]  = sum_n E[n][m]*V[bh][n][d]  (single bf16 out, transposed)
__global__ __launch_bounds__(256) void proj_kernel(const float* __restrict__ K,
                                                   const float* __restrict__ V,
                                                   const unsigned short* __restrict__ Et_hi,
                                                   const unsigned short* __restrict__ Et_lo,
                                                   unsigned short* __restrict__ Kp_hi,
                                                   unsigned short* __restrict__ Kp_lo,
                                                   unsigned short* __restrict__ Vpt){
    __shared__ unsigned short Eh[64][72], El[64][72], Kh[64][72], Kl[64][72], Vh[64][72];
    int bid  = blockIdx.x;
    int orig = (bid & 7) * 32 + (bid >> 3);   // XCD-chunked: same-head blocks on same XCD
    int bh   = orig >> 2;
    int m0   = (orig & 3) * 64;
    int t = threadIdx.x;
    int w = t >> 6, l = t & 63, l15 = l & 15, lg = l >> 4;

    const float* Kb = K + (size_t)bh * SEQ * DIM;
    const float* Vb = V + (size_t)bh * SEQ * DIM;

    f32x4 accK[4], accV[4];
    #pragma unroll
    for (int i = 0; i < 4; ++i){ accK[i] = (f32x4)0.0f; accV[i] = (f32x4)0.0f; }

    for (int n0 = 0; n0 < SEQ; n0 += 64){
        // stage Et hi/lo tile [64 m][64 n] (rows padded to 72)
        #pragma unroll
        for (int r = 0; r < 2; ++r){
            int ml = (t >> 3) + r * 32;
            int s  = t & 7;
            const int4* ph = reinterpret_cast<const int4*>(Et_hi + (size_t)(m0 + ml) * SEQ + n0 + s * 8);
            const int4* pl = reinterpret_cast<const int4*>(Et_lo + (size_t)(m0 + ml) * SEQ + n0 + s * 8);
            *reinterpret_cast<int4*>(&Eh[ml][s * 8]) = *ph;
            *reinterpret_cast<int4*>(&El[ml][s * 8]) = *pl;
        }
        // stage K/V transposed + split: [d][n]
        {
            int d  = t & 63;
            int ng = t >> 6;
            #pragma unroll
            for (int p = 0; p < 2; ++p){
                int nb = p * 32 + ng * 8;
                u16x8 kh, kl, vh;
                #pragma unroll
                for (int i = 0; i < 8; ++i){
                    float kv = Kb[(size_t)(n0 + nb + i) * DIM + d];
                    unsigned short h = f2bf(kv);
                    kh[i] = (short)h;
                    kl[i] = (short)f2bf(kv - bf2f(h));
                    float vv = Vb[(size_t)(n0 + nb + i) * DIM + d];
                    vh[i] = (short)f2bf(vv);
                }
                *reinterpret_cast<u16x8*>(&Kh[d][nb]) = kh;
                *reinterpret_cast<u16x8*>(&Kl[d][nb]) = kl;
                *reinterpret_cast<u16x8*>(&Vh[d][nb]) = vh;
            }
        }
        __syncthreads();
        #pragma unroll
        for (int nk = 0; nk < 2; ++nk){
            int kb = nk * 32 + lg * 8;
            bf16x8 eh[4], el[4];
            #pragma unroll
            for (int ms = 0; ms < 4; ++ms){
                eh[ms] = *reinterpret_cast<const bf16x8*>(&Eh[ms * 16 + l15][kb]);
                el[ms] = *reinterpret_cast<const bf16x8*>(&El[ms * 16 + l15][kb]);
            }
            bf16x8 kh = *reinterpret_cast<const bf16x8*>(&Kh[w * 16 + l15][kb]);
            bf16x8 kl = *reinterpret_cast<const bf16x8*>(&Kl[w * 16 + l15][kb]);
            bf16x8 vh = *reinterpret_cast<const bf16x8*>(&Vh[w * 16 + l15][kb]);
            #pragma unroll
            for (int ms = 0; ms < 4; ++ms){
                accK[ms] = __builtin_amdgcn_mfma_f32_16x16x32_bf16(eh[ms], kh, accK[ms], 0, 0, 0);
                accK[ms] = __builtin_amdgcn_mfma_f32_16x16x32_bf16(eh[ms], kl, accK[ms], 0, 0, 0);
                accK[ms] = __builtin_amdgcn_mfma_f32_16x16x32_bf16(el[ms], kh, accK[ms], 0, 0, 0);
                accV[ms] = __builtin_amdgcn_mfma_f32_16x16x32_bf16(vh, eh[ms], accV[ms], 0, 0, 0);
            }
        }
        __syncthreads();
    }

    // epilogue: split K_proj, write Vpt transposed
    #pragma unroll
    for (int ms = 0; ms < 4; ++ms){
        #pragma unroll
        for (int j = 0; j < 4; ++j){
            float kv = accK[ms][j];
            int mg = m0 + ms * 16 + lg * 4 + j;
            int dg = w * 16 + l15;
            unsigned short h = f2bf(kv);
            size_t o = ((size_t)bh * PM + mg) * DIM + dg;
            Kp_hi[o] = h;
            Kp_lo[o] = f2bf(kv - bf2f(h));
            float vv = accV[ms][j];
            int dr = w * 16 + lg * 4 + j;
            int mc = m0 + ms * 16 + l15;
            Vpt[((size_t)bh * DIM + dr) * PM + mc] = f2bf(vv);
        }
    }
}

// ---------------- kernel 3: attention ----------------
__global__ __launch_bounds__(256) void attn_kernel(const float* __restrict__ Q,
                                                   const unsigned short* __restrict__ Kp_hi,
                                                   const unsigned short* __restrict__ Kp_lo,
                                                   const unsigned short* __restrict__ Vpt,
                                                   float* __restrict__ Out){
    __shared__ unsigned short SQh[64][72], SQl[64][72];
    __shared__ unsigned short SB[2 * 128 * 72];  // Kp staging; later reused as P[64][264]
    unsigned short (*SBh)[72] = reinterpret_cast<unsigned short (*)[72]>(SB);
    unsigned short (*SBl)[72] = reinterpret_cast<unsigned short (*)[72]>(SB + 128 * 72);
    unsigned short (*P)[264]  = reinterpret_cast<unsigned short (*)[264]>(SB);

    int bid  = blockIdx.x;
    int orig = (bid & 7) * 512 + (bid >> 3);  // XCD-chunked: same-head blocks on same XCD
    int bh   = orig >> 6;
    int q0   = (orig & 63) * 64;
    int t = threadIdx.x;
    int w = t >> 6, l = t & 63, l15 = l & 15, lg = l >> 4;

    // stage Q*(1/8) split hi/lo  [64 q][64 d]
    #pragma unroll
    for (int r = 0; r < 2; ++r){
        int q = (t >> 3) + r * 32;
        int s = t & 7;
        const float* src = Q + ((size_t)bh * SEQ + q0 + q) * DIM + s * 8;
        float4 a = *reinterpret_cast<const float4*>(src);
        float4 b = *reinterpret_cast<const float4*>(src + 4);
        float vals[8] = {a.x, a.y, a.z, a.w, b.x, b.y, b.z, b.w};
        u16x8 hi, lo;
        #pragma unroll
        for (int i = 0; i < 8; ++i){
            float v = vals[i] * 0.125f;   // exact scale, fold 1/sqrt(D)
            unsigned short h = f2bf(v);
            hi[i] = h;
            lo[i] = f2bf(v - bf2f(h));
        }
        *reinterpret_cast<u16x8*>(&SQh[q][s * 8]) = hi;
        *reinterpret_cast<u16x8*>(&SQl[q][s * 8]) = lo;
    }

    f32x4 sa[16];
    #pragma unroll
    for (int i = 0; i < 16; ++i) sa[i] = (f32x4)0.0f;
    bf16x8 qh[2], ql[2];

    #pragma unroll
    for (int mh = 0; mh < 2; ++mh){
        // stage Kp half [128 m][64 d] hi/lo
        {
            int ml = t >> 1;
            int hf = t & 1;
            const unsigned short* sh = Kp_hi + ((size_t)bh * PM + mh * 128 + ml) * DIM + hf * 32;
            const unsigned short* sl = Kp_lo + ((size_t)bh * PM + mh * 128 + ml) * DIM + hf * 32;
            #pragma unroll
            for (int c = 0; c < 4; ++c){
                *reinterpret_cast<int4*>(&SBh[ml][hf * 32 + c * 8]) = *reinterpret_cast<const int4*>(sh + c * 8);
                *reinterpret_cast<int4*>(&SBl[ml][hf * 32 + c * 8]) = *reinterpret_cast<const int4*>(sl + c * 8);
            }
        }
        __syncthreads();
        if (mh == 0){
            #pragma unroll
            for (int nk = 0; nk < 2; ++nk){
                qh[nk] = *reinterpret_cast<const bf16x8*>(&SQh[w * 16 + l15][nk * 32 + lg * 8]);
                ql[nk] = *reinterpret_cast<const bf16x8*>(&SQl[w * 16 + l15][nk * 32 + lg * 8]);
            }
        }
        #pragma unroll
        for (int nk = 0; nk < 2; ++nk){
            #pragma unroll
            for (int mt = 0; mt < 8; ++mt){
                bf16x8 bh_ = *reinterpret_cast<const bf16x8*>(&SBh[mt * 16 + l15][nk * 32 + lg * 8]);
                bf16x8 bl_ = *reinterpret_cast<const bf16x8*>(&SBl[mt * 16 + l15][nk * 32 + lg * 8]);
                int mi = mh * 8 + mt;
                sa[mi] = __builtin_amdgcn_mfma_f32_16x16x32_bf16(qh[nk], bh_, sa[mi], 0, 0, 0);
                sa[mi] = __builtin_amdgcn_mfma_f32_16x16x32_bf16(qh[nk], bl_, sa[mi], 0, 0, 0);
                sa[mi] = __builtin_amdgcn_mfma_f32_16x16x32_bf16(ql[nk], bh_, sa[mi], 0, 0, 0);
            }
        }
        __syncthreads();
    }

    // softmax over m=256: per lane-group row j, cols spread over 16 lanes x 16 regs
    float inv[4];
    #pragma unroll
    for (int j = 0; j < 4; ++j){
        float mx = sa[0][j];
        #pragma unroll
        for (int mi = 1; mi < 16; ++mi) mx = fmaxf(mx, sa[mi][j]);
        #pragma unroll
        for (int o = 1; o < 16; o <<= 1) mx = fmaxf(mx, __shfl_xor(mx, o, 64));
        float sum = 0.0f;
        #pragma unroll
        for (int mi = 0; mi < 16; ++mi){
            float p = __expf(sa[mi][j] - mx);
            sa[mi][j] = p;
            sum += p;
        }
        #pragma unroll
        for (int o = 1; o < 16; o <<= 1) sum += __shfl_xor(sum, o, 64);
        inv[j] = 1.0f / sum;
    }

    // redistribute P through LDS (overlays Kp staging; already synced)
    #pragma unroll
    for (int mi = 0; mi < 16; ++mi){
        #pragma unroll
        for (int j = 0; j < 4; ++j){
            P[w * 16 + lg * 4 + j][mi * 16 + l15] = f2bf(sa[mi][j]);
        }
    }
    __syncthreads();

    // PV: out[q][d] = sum_m P[q][m] * Vpt[d][m]
    f32x4 oacc[4];
    #pragma unroll
    for (int i = 0; i < 4; ++i) oacc[i] = (f32x4)0.0f;
    const unsigned short* Vb = Vpt + (size_t)bh * DIM * PM;
    #pragma unroll
    for (int mk = 0; mk < 8; ++mk){
        bf16x8 ap = *reinterpret_cast<const bf16x8*>(&P[w * 16 + l15][mk * 32 + lg * 8]);
        #pragma unroll
        for (int dt = 0; dt < 4; ++dt){
            bf16x8 bv = *reinterpret_cast<const bf16x8*>(Vb + (size_t)(dt * 16 + l15) * PM + mk * 32 + lg * 8);
            oacc[dt] = __builtin_amdgcn_mfma_f32_16x16x32_bf16(ap, bv, oacc[dt], 0, 0, 0);
        }
    }

    #pragma unroll
    for (int dt = 0; dt < 4; ++dt){
        #pragma unroll
        for (int j = 0; j < 4; ++j){
            int qg = q0 + w * 16 + lg * 4 + j;
            Out[((size_t)bh * SEQ + qg) * DIM + dt * 16 + l15] = oacc[dt][j] * inv[j];
        }
    }
}

extern "C" void kernel_launch(void* const* d_in, const int* in_sizes, int n_in,
                              void* d_out, int out_size, void* d_ws, size_t ws_size,
                              hipStream_t stream){
    const float* Q = (const float*)d_in[0];
    const float* K = (const float*)d_in[1];
    const float* V = (const float*)d_in[2];
    const float* E = (const float*)d_in[3];
    float* out = (float*)d_out;

    unsigned short* Et_hi = (unsigned short*)d_ws;                       // [M][N]
    unsigned short* Et_lo = Et_hi + (size_t)PM * SEQ;                    // [M][N]
    unsigned short* Kp_hi = Et_lo + (size_t)PM * SEQ;                    // [BH][M][D]
    unsigned short* Kp_lo = Kp_hi + (size_t)BH * PM * DIM;               // [BH][M][D]
    unsigned short* Vpt   = Kp_lo + (size_t)BH * PM * DIM;               // [BH][D][M]

    prep_e_kernel<<<256, 256, 0, stream>>>(E, Et_hi, Et_lo);
    proj_kernel<<<256, 256, 0, stream>>>(K, V, Et_hi, Et_lo, Kp_hi, Kp_lo, Vpt);
    attn_kernel<<<4096, 256, 0, stream>>>(Q, Kp_hi, Kp_lo, Vpt, out);
}